// Round 3
// baseline (299.597 us; speedup 1.0000x reference)
//
#include <hip/hip_runtime.h>
#include <math.h>

#define D_PROJ 8192
#define C_IN   512
#define P_SP   196   // 14*14
#define NBATCH 32

// ---------------------------------------------------------------------------
// Recover both count-sketches in one pass. S1,S2: [512, 8192], one nonzero
// (+-1) per row at column h[row]. Writes packed  h | (s<0 ? 0x8000 : 0).
// ---------------------------------------------------------------------------
__global__ __launch_bounds__(256) void extract_both(
    const float* __restrict__ S1, const float* __restrict__ S2,
    int* __restrict__ p1, int* __restrict__ p2)
{
    const int total4 = 2 * C_IN * (D_PROJ / 4);      // 2,097,152 float4
    for (int idx = blockIdx.x * 256 + threadIdx.x; idx < total4;
         idx += gridDim.x * 256) {
        const int m   = idx >> 20;                   // 0: S1, 1: S2
        const int rem = idx & 1048575;
        const float4 v = ((const float4*)(m ? S2 : S1))[rem];
        if (v.x != 0.f || v.y != 0.f || v.z != 0.f || v.w != 0.f) {
            const int row = rem >> 11;               // 2048 float4 per row
            const int c4  = (rem & 2047) << 2;
            float val; int c;
            if      (v.x != 0.f) { val = v.x; c = c4;     }
            else if (v.y != 0.f) { val = v.y; c = c4 + 1; }
            else if (v.z != 0.f) { val = v.z; c = c4 + 2; }
            else                 { val = v.w; c = c4 + 3; }
            const int packed = c | (val < 0.f ? 0x8000 : 0);
            (m ? p2 : p1)[row] = packed;
        }
    }
}

// ---------------------------------------------------------------------------
// x[b][c][p] -> xT[b][p][c]  (p = 196, c = 512).
// ---------------------------------------------------------------------------
__global__ __launch_bounds__(256) void transpose_x(
    const float* __restrict__ x, float* __restrict__ xT)
{
    __shared__ float tile[32][33];
    const int b  = blockIdx.z;
    const int c0 = blockIdx.y * 32;
    const int p0 = blockIdx.x * 32;
    const int tx = threadIdx.x & 31;
    const int ty = threadIdx.x >> 5;
    #pragma unroll
    for (int k = 0; k < 4; ++k) {
        const int p = p0 + tx, c = c0 + ty + k * 8;
        if (p < P_SP) tile[ty + k * 8][tx] = x[((size_t)b * C_IN + c) * P_SP + p];
    }
    __syncthreads();
    #pragma unroll
    for (int k = 0; k < 4; ++k) {
        const int p = p0 + ty + k * 8, c = c0 + tx;
        if (p < P_SP) xT[((size_t)b * P_SP + p) * C_IN + c] = tile[tx][ty + k * 8];
    }
}

// ---------------------------------------------------------------------------
// Fused Gram + count-sketch scatter. Block = (jt, it, b*2+kh); 128x128 G tile
// over a 98-deep K half, 8x8 register microtile, LDS 8192-bin histogram,
// then a PLAIN float4 stream of the private histogram into ws (no global
// atomics -- round-2's 364 MB atomic write amplification was the bottleneck).
// ---------------------------------------------------------------------------
#define PCH 7

__global__ __launch_bounds__(256, 4) void gram_scatter(
    const float* __restrict__ xT,
    const int* __restrict__ P1, const int* __restrict__ P2,
    float* __restrict__ partials)
{
    __shared__ float hist[D_PROJ];                       // 32 KB
    __shared__ __align__(16) float As[PCH * 128];        // 3.5 KB, p-major
    __shared__ __align__(16) float Bs[PCH * 128];
    __shared__ unsigned short p1L[128], p2L[128];        // packed h|sign<<15

    const int tid = threadIdx.x;
    const int tx  = tid & 15;           // j quad
    const int ty  = tid >> 4;           // i quad
    const int jt  = blockIdx.x;         // j tile (0..3)
    const int it  = blockIdx.y;         // i tile (0..3)
    const int b   = blockIdx.z >> 1;
    const int kh  = blockIdx.z & 1;     // K half (p in [kh*98, kh*98+98))

    if (tid < 128) {
        p1L[tid] = (unsigned short)P1[it * 128 + tid];
        p2L[tid] = (unsigned short)P2[jt * 128 + tid];
    }
    {   // zero histogram (float4)
        float4* h4 = (float4*)hist;
        const float4 z = make_float4(0.f, 0.f, 0.f, 0.f);
        #pragma unroll
        for (int k = 0; k < 8; ++k) h4[tid + k * 256] = z;
    }

    const float* xb = xT + (size_t)b * P_SP * C_IN;
    const int iofs = it * 128, jofs = jt * 128;

    float acc[8][8];
    #pragma unroll
    for (int r = 0; r < 8; ++r)
        #pragma unroll
        for (int c = 0; c < 8; ++c) acc[r][c] = 0.0f;

    for (int ck = 0; ck < 14; ++ck) {
        const int p0 = kh * 98 + ck * PCH;
        __syncthreads();   // 1st iter: covers hist zero + param staging
        // stage 2*224 float4 across 256 threads
        if (tid < 224) {
            const int pp = tid >> 5, cc = (tid & 31) * 4;
            *(float4*)(As + pp * 128 + cc) =
                *(const float4*)(xb + (size_t)(p0 + pp) * C_IN + iofs + cc);
        } else {
            const int f = tid - 224;
            const int pp = f >> 5, cc = (f & 31) * 4;
            *(float4*)(Bs + pp * 128 + cc) =
                *(const float4*)(xb + (size_t)(p0 + pp) * C_IN + jofs + cc);
        }
        if (tid < 192) {
            const int f = tid + 32;
            const int pp = f >> 5, cc = (f & 31) * 4;
            *(float4*)(Bs + pp * 128 + cc) =
                *(const float4*)(xb + (size_t)(p0 + pp) * C_IN + jofs + cc);
        }
        __syncthreads();
        #pragma unroll
        for (int pp = 0; pp < PCH; ++pp) {
            const float* ap = As + pp * 128;
            const float* bp = Bs + pp * 128;
            const float4 a0 = *(const float4*)(ap + ty * 4);
            const float4 a1 = *(const float4*)(ap + 64 + ty * 4);
            const float4 b0 = *(const float4*)(bp + tx * 4);
            const float4 b1 = *(const float4*)(bp + 64 + tx * 4);
            const float av[8] = {a0.x, a0.y, a0.z, a0.w, a1.x, a1.y, a1.z, a1.w};
            const float bv[8] = {b0.x, b0.y, b0.z, b0.w, b1.x, b1.y, b1.z, b1.w};
            #pragma unroll
            for (int r = 0; r < 8; ++r)
                #pragma unroll
                for (int c = 0; c < 8; ++c)
                    acc[r][c] = fmaf(av[r], bv[c], acc[r][c]);
        }
    }

    // scatter: bin = (h1+h2)&8191; sign parity lives at bit 15 of the sum
    int pa[8], pb[8];
    #pragma unroll
    for (int r = 0; r < 8; ++r) {
        const int il = (r < 4) ? (ty * 4 + r) : (64 + ty * 4 + r - 4);
        pa[r] = p1L[il];
    }
    #pragma unroll
    for (int c = 0; c < 8; ++c) {
        const int jl = (c < 4) ? (tx * 4 + c) : (64 + tx * 4 + c - 4);
        pb[c] = p2L[jl];
    }
    #pragma unroll
    for (int r = 0; r < 8; ++r)
        #pragma unroll
        for (int c = 0; c < 8; ++c) {
            const int sum = pa[r] + pb[c];
            const int d   = sum & (D_PROJ - 1);
            const float v = __int_as_float(
                __float_as_int(acc[r][c]) ^ ((sum << 16) & 0x80000000));
            atomicAdd(&hist[d], v);
        }
    __syncthreads();

    // plain streaming store of the private histogram (no global atomics)
    const int part = (b * 32) + (kh * 16) + (it * 4) + jt;
    float4* pm = (float4*)(partials + (size_t)part * D_PROJ);
    const float4* h4 = (const float4*)hist;
    #pragma unroll
    for (int k = 0; k < 8; ++k) pm[tid + k * 256] = h4[tid + k * 256];
}

// ---------------------------------------------------------------------------
// Sum the 32 partial histograms per batch -> pool (written into d_out), and
// accumulate per-batch sum(|pool|) into normsq (one atomic per block).
// grid (32 d-chunks, 32 batches).
// ---------------------------------------------------------------------------
__global__ __launch_bounds__(256) void reduce_norm(
    const float* __restrict__ partials, float* __restrict__ pool,
    float* __restrict__ normsq)
{
    const int b = blockIdx.y;
    const int d = blockIdx.x * 256 + threadIdx.x;
    const float* base = partials + ((size_t)b * 32) * D_PROJ + d;
    float s = 0.0f;
    #pragma unroll
    for (int p = 0; p < 32; ++p) s += base[(size_t)p * D_PROJ];
    pool[(size_t)b * D_PROJ + d] = s;

    float a = fabsf(s);
    #pragma unroll
    for (int off = 32; off > 0; off >>= 1) a += __shfl_down(a, off, 64);
    __shared__ float red[4];
    const int tid = threadIdx.x;
    if ((tid & 63) == 0) red[tid >> 6] = a;
    __syncthreads();
    if (tid == 0) atomicAdd(&normsq[b], red[0] + red[1] + red[2] + red[3]);
}

// ---------------------------------------------------------------------------
// Per-batch in-place: out = sign(p)*sqrt(|p|+1e-8) / sqrt(sum|p| + 8192e-8)
// ---------------------------------------------------------------------------
__global__ __launch_bounds__(256) void finalize_kernel(
    float* __restrict__ out, const float* __restrict__ normsq)
{
    const int b = blockIdx.x;
    float4* p = (float4*)(out + (size_t)b * D_PROJ);
    const int tid = threadIdx.x;
    const float inv =
        1.0f / fmaxf(sqrtf(normsq[b] + (float)D_PROJ * 1e-8f), 1e-12f);

    #pragma unroll
    for (int k = 0; k < 8; ++k) {
        float4 w = p[tid + k * 256];
        float* e = (float*)&w;
        #pragma unroll
        for (int q = 0; q < 4; ++q) {
            const float x = e[q];
            const float r = sqrtf(fabsf(x) + 1e-8f) * inv;
            e[q] = (x > 0.f) ? r : ((x < 0.f) ? -r : 0.f);
        }
        p[tid + k * 256] = w;
    }
}

// ---------------------------------------------------------------------------
extern "C" void kernel_launch(void* const* d_in, const int* in_sizes, int n_in,
                              void* d_out, int out_size, void* d_ws, size_t ws_size,
                              hipStream_t stream)
{
    const float* x  = (const float*)d_in[0];   // [32, 512, 14, 14]
    const float* S1 = (const float*)d_in[1];   // [512, 8192]
    const float* S2 = (const float*)d_in[2];   // [512, 8192]
    float* out = (float*)d_out;                // [32, 8192]

    char* ws = (char*)d_ws;
    int*   p1     = (int*)(ws);                        // 2 KB
    int*   p2     = (int*)(ws + 2048);                 // 2 KB
    float* normsq = (float*)(ws + 4096);               // 128 B
    float* xT     = (float*)(ws + 8192);               // 12.8 MB
    float* parts  = (float*)(ws + 8192 + 12845056);    // 33.5 MB (1024 x 8192)

    hipMemsetAsync(normsq, 0, NBATCH * sizeof(float), stream);
    extract_both<<<1024, 256, 0, stream>>>(S1, S2, p1, p2);
    transpose_x<<<dim3(7, 16, NBATCH), 256, 0, stream>>>(x, xT);
    gram_scatter<<<dim3(4, 4, NBATCH * 2), 256, 0, stream>>>(xT, p1, p2, parts);
    reduce_norm<<<dim3(32, NBATCH), 256, 0, stream>>>(parts, out, normsq);
    finalize_kernel<<<NBATCH, 256, 0, stream>>>(out, normsq);
}

// Round 4
// 225.146 us; speedup vs baseline: 1.3307x; 1.3307x over previous
//
#include <hip/hip_runtime.h>
#include <math.h>

#define D_PROJ 8192
#define C_IN   512
#define P_SP   196   // 14*14
#define NBATCH 32

#define TR_BLOCKS (7 * 16 * NBATCH)   // 3584 transpose blocks
#define EX_BLOCKS 1024                // extract blocks

// ---------------------------------------------------------------------------
// Fused prep: (a) transpose x[b][c][p] -> xT[b][p][c]; (b) recover both
// count-sketches from dense S1/S2 into packed h | (s<0 ? 0x8000 : 0).
// ---------------------------------------------------------------------------
__global__ __launch_bounds__(256) void prep(
    const float* __restrict__ x,
    const float* __restrict__ S1, const float* __restrict__ S2,
    float* __restrict__ xT, int* __restrict__ p1, int* __restrict__ p2)
{
    __shared__ float tile[32][33];
    const int bid = blockIdx.x;

    if (bid < TR_BLOCKS) {
        const int b  = bid / 112;
        const int r  = bid - b * 112;
        const int cb = r / 7;
        const int c0 = cb * 32;
        const int p0 = (r - cb * 7) * 32;
        const int tx = threadIdx.x & 31;
        const int ty = threadIdx.x >> 5;
        #pragma unroll
        for (int k = 0; k < 4; ++k) {
            const int p = p0 + tx, c = c0 + ty + k * 8;
            if (p < P_SP)
                tile[ty + k * 8][tx] = x[((size_t)b * C_IN + c) * P_SP + p];
        }
        __syncthreads();
        #pragma unroll
        for (int k = 0; k < 4; ++k) {
            const int p = p0 + ty + k * 8, c = c0 + tx;
            if (p < P_SP)
                xT[((size_t)b * P_SP + p) * C_IN + c] = tile[tx][ty + k * 8];
        }
    } else {
        const int total4 = 2 * C_IN * (D_PROJ / 4);      // 2,097,152 float4
        for (int idx = (bid - TR_BLOCKS) * 256 + threadIdx.x; idx < total4;
             idx += EX_BLOCKS * 256) {
            const int m   = idx >> 20;                   // 0: S1, 1: S2
            const int rem = idx & 1048575;
            const float4 v = ((const float4*)(m ? S2 : S1))[rem];
            if (v.x != 0.f || v.y != 0.f || v.z != 0.f || v.w != 0.f) {
                const int row = rem >> 11;               // 2048 float4 / row
                const int c4  = (rem & 2047) << 2;
                float val; int c;
                if      (v.x != 0.f) { val = v.x; c = c4;     }
                else if (v.y != 0.f) { val = v.y; c = c4 + 1; }
                else if (v.z != 0.f) { val = v.z; c = c4 + 2; }
                else                 { val = v.w; c = c4 + 3; }
                (m ? p2 : p1)[row] = c | (val < 0.f ? 0x8000 : 0);
            }
        }
    }
}

// ---------------------------------------------------------------------------
// Fused Gram + count-sketch scatter. Block = (jt, it, b*2+kh); 128x128 G tile
// over a 98-deep K half, 8x8 register microtile, LDS 8192-bin histogram,
// float4 stream of the private histogram into ws.
// NOTE: no min-waves in __launch_bounds__ — forcing 4 waves/EU capped VGPRs
// at 64 and spilled acc[8][8] to scratch (the ~380 MB HBM write in R2/R3).
// ---------------------------------------------------------------------------
#define PCH 7

__global__ __launch_bounds__(256) void gram_scatter(
    const float* __restrict__ xT,
    const int* __restrict__ P1, const int* __restrict__ P2,
    float* __restrict__ partials)
{
    __shared__ float hist[D_PROJ];                       // 32 KB
    __shared__ __align__(16) float As[PCH * 128];        // 3.5 KB, p-major
    __shared__ __align__(16) float Bs[PCH * 128];
    __shared__ unsigned short p1L[128], p2L[128];        // packed h|sign<<15

    const int tid = threadIdx.x;
    const int tx  = tid & 15;           // j quad
    const int ty  = tid >> 4;           // i quad
    const int jt  = blockIdx.x;         // j tile (0..3)
    const int it  = blockIdx.y;         // i tile (0..3)
    const int b   = blockIdx.z >> 1;
    const int kh  = blockIdx.z & 1;     // K half (p in [kh*98, kh*98+98))

    if (tid < 128) {
        p1L[tid] = (unsigned short)P1[it * 128 + tid];
        p2L[tid] = (unsigned short)P2[jt * 128 + tid];
    }
    {   // zero histogram (float4)
        float4* h4 = (float4*)hist;
        const float4 z = make_float4(0.f, 0.f, 0.f, 0.f);
        #pragma unroll
        for (int k = 0; k < 8; ++k) h4[tid + k * 256] = z;
    }

    const float* xb = xT + (size_t)b * P_SP * C_IN;
    const int iofs = it * 128, jofs = jt * 128;

    float acc[8][8];
    #pragma unroll
    for (int r = 0; r < 8; ++r)
        #pragma unroll
        for (int c = 0; c < 8; ++c) acc[r][c] = 0.0f;

    for (int ck = 0; ck < 14; ++ck) {
        const int p0 = kh * 98 + ck * PCH;
        __syncthreads();   // 1st iter: covers hist zero + param staging
        // stage 2*224 float4 across 256 threads
        if (tid < 224) {
            const int pp = tid >> 5, cc = (tid & 31) * 4;
            *(float4*)(As + pp * 128 + cc) =
                *(const float4*)(xb + (size_t)(p0 + pp) * C_IN + iofs + cc);
        } else {
            const int f = tid - 224;
            const int pp = f >> 5, cc = (f & 31) * 4;
            *(float4*)(Bs + pp * 128 + cc) =
                *(const float4*)(xb + (size_t)(p0 + pp) * C_IN + jofs + cc);
        }
        if (tid < 192) {
            const int f = tid + 32;
            const int pp = f >> 5, cc = (f & 31) * 4;
            *(float4*)(Bs + pp * 128 + cc) =
                *(const float4*)(xb + (size_t)(p0 + pp) * C_IN + jofs + cc);
        }
        __syncthreads();
        #pragma unroll
        for (int pp = 0; pp < PCH; ++pp) {
            const float* ap = As + pp * 128;
            const float* bp = Bs + pp * 128;
            const float4 a0 = *(const float4*)(ap + ty * 4);
            const float4 a1 = *(const float4*)(ap + 64 + ty * 4);
            const float4 b0 = *(const float4*)(bp + tx * 4);
            const float4 b1 = *(const float4*)(bp + 64 + tx * 4);
            const float av[8] = {a0.x, a0.y, a0.z, a0.w, a1.x, a1.y, a1.z, a1.w};
            const float bv[8] = {b0.x, b0.y, b0.z, b0.w, b1.x, b1.y, b1.z, b1.w};
            #pragma unroll
            for (int r = 0; r < 8; ++r)
                #pragma unroll
                for (int c = 0; c < 8; ++c)
                    acc[r][c] = fmaf(av[r], bv[c], acc[r][c]);
        }
    }

    // scatter: bin = (h1+h2)&8191; sign parity lives at bit 15 of the sum
    int pa[8], pb[8];
    #pragma unroll
    for (int r = 0; r < 8; ++r) {
        const int il = (r < 4) ? (ty * 4 + r) : (64 + ty * 4 + r - 4);
        pa[r] = p1L[il];
    }
    #pragma unroll
    for (int c = 0; c < 8; ++c) {
        const int jl = (c < 4) ? (tx * 4 + c) : (64 + tx * 4 + c - 4);
        pb[c] = p2L[jl];
    }
    #pragma unroll
    for (int r = 0; r < 8; ++r)
        #pragma unroll
        for (int c = 0; c < 8; ++c) {
            const int sum = pa[r] + pb[c];
            const int d   = sum & (D_PROJ - 1);
            const float v = __int_as_float(
                __float_as_int(acc[r][c]) ^ ((sum << 16) & 0x80000000));
            atomicAdd(&hist[d], v);
        }
    __syncthreads();

    // plain streaming store of the private histogram (no global atomics)
    const int part = (b * 32) + (kh * 16) + (it * 4) + jt;
    float4* pm = (float4*)(partials + (size_t)part * D_PROJ);
    const float4* h4 = (const float4*)hist;
    #pragma unroll
    for (int k = 0; k < 8; ++k) pm[tid + k * 256] = h4[tid + k * 256];
}

// ---------------------------------------------------------------------------
// Sum the 32 partial histograms per batch -> pool (in d_out); write the
// per-(b,chunk) sum(|.|) partial into normpart (no atomics, no memset).
// grid (32 d-chunks, 32 batches).
// ---------------------------------------------------------------------------
__global__ __launch_bounds__(256) void reduce_norm(
    const float* __restrict__ partials, float* __restrict__ pool,
    float* __restrict__ normpart)
{
    const int b = blockIdx.y;
    const int d = blockIdx.x * 256 + threadIdx.x;
    const float* base = partials + ((size_t)b * 32) * D_PROJ + d;
    float s = 0.0f;
    #pragma unroll
    for (int p = 0; p < 32; ++p) s += base[(size_t)p * D_PROJ];
    pool[(size_t)b * D_PROJ + d] = s;

    float a = fabsf(s);
    #pragma unroll
    for (int off = 32; off > 0; off >>= 1) a += __shfl_down(a, off, 64);
    __shared__ float red[4];
    const int tid = threadIdx.x;
    if ((tid & 63) == 0) red[tid >> 6] = a;
    __syncthreads();
    if (tid == 0)
        normpart[b * 32 + blockIdx.x] = red[0] + red[1] + red[2] + red[3];
}

// ---------------------------------------------------------------------------
// Per-batch in-place: out = sign(p)*sqrt(|p|+1e-8) / sqrt(sum|p| + 8192e-8)
// ---------------------------------------------------------------------------
__global__ __launch_bounds__(256) void finalize_kernel(
    float* __restrict__ out, const float* __restrict__ normpart)
{
    const int b = blockIdx.x;
    float4* p = (float4*)(out + (size_t)b * D_PROJ);
    const int tid = threadIdx.x;

    float total = 0.0f;
    #pragma unroll
    for (int k = 0; k < 32; ++k) total += normpart[b * 32 + k];
    const float inv =
        1.0f / fmaxf(sqrtf(total + (float)D_PROJ * 1e-8f), 1e-12f);

    #pragma unroll
    for (int k = 0; k < 8; ++k) {
        float4 w = p[tid + k * 256];
        float* e = (float*)&w;
        #pragma unroll
        for (int q = 0; q < 4; ++q) {
            const float x = e[q];
            const float r = sqrtf(fabsf(x) + 1e-8f) * inv;
            e[q] = (x > 0.f) ? r : ((x < 0.f) ? -r : 0.f);
        }
        p[tid + k * 256] = w;
    }
}

// ---------------------------------------------------------------------------
extern "C" void kernel_launch(void* const* d_in, const int* in_sizes, int n_in,
                              void* d_out, int out_size, void* d_ws, size_t ws_size,
                              hipStream_t stream)
{
    const float* x  = (const float*)d_in[0];   // [32, 512, 14, 14]
    const float* S1 = (const float*)d_in[1];   // [512, 8192]
    const float* S2 = (const float*)d_in[2];   // [512, 8192]
    float* out = (float*)d_out;                // [32, 8192]

    char* ws = (char*)d_ws;
    int*   p1       = (int*)(ws);                      // 2 KB
    int*   p2       = (int*)(ws + 2048);               // 2 KB
    float* normpart = (float*)(ws + 4096);             // 4 KB (32x32)
    float* xT       = (float*)(ws + 8192);             // 12.8 MB
    float* parts    = (float*)(ws + 8192 + 12845056);  // 33.5 MB (1024x8192)

    prep<<<TR_BLOCKS + EX_BLOCKS, 256, 0, stream>>>(x, S1, S2, xT, p1, p2);
    gram_scatter<<<dim3(4, 4, NBATCH * 2), 256, 0, stream>>>(xT, p1, p2, parts);
    reduce_norm<<<dim3(32, NBATCH), 256, 0, stream>>>(parts, out, normpart);
    finalize_kernel<<<NBATCH, 256, 0, stream>>>(out, normpart);
}